// Round 11
// baseline (68.728 us; speedup 1.0000x reference)
//
#include <hip/hip_runtime.h>
#include <hip/hip_bf16.h>

#define T_STEPS 128
#define BATCH   2048
#define IN_F    64
#define HID     256
#define OUT_F   16
#define CH      8                  // timesteps per staged x chunk / reduce group
#define NCH     (T_STEPS / CH)     // 16 chunks
#define SLAB    (BATCH * OUT_F)

typedef __attribute__((ext_vector_type(8))) short bf16x8;
typedef __attribute__((ext_vector_type(4))) float f32x4;
typedef unsigned short u16;
typedef unsigned int   u32;

__device__ __forceinline__ u16 f2bf(float f) {      // RNE via HW cvt (pk-fusable)
    union { __hip_bfloat16 h; u16 u; } cv;
    cv.h = __float2bfloat16(f);
    return cv.u;
}
__device__ __forceinline__ float bf2f(u16 h) {
    return __uint_as_float(((u32)h) << 16);
}
__device__ __forceinline__ bf16x8 pack8(float4 a, float4 b) {
    bf16x8 r;
    r[0] = (short)f2bf(a.x); r[1] = (short)f2bf(a.y);
    r[2] = (short)f2bf(a.z); r[3] = (short)f2bf(a.w);
    r[4] = (short)f2bf(b.x); r[5] = (short)f2bf(b.y);
    r[6] = (short)f2bf(b.z); r[7] = (short)f2bf(b.w);
    return r;
}

// Zero the spikes_mean accumulator (d_out not re-poisoned between replays).
__global__ void snn_init_kernel(float* __restrict__ out) {
    if (threadIdx.x == 0 && blockIdx.x == 0) out[BATCH * OUT_F] = 0.0f;
}

// Kernel 1: R10 structure reshaped for pipe overlap. Block = 16 rows x 64 hid
// (4 waves x 16 hid), 48 KB LDS -> TWO independent blocks per CU drifting out
// of phase (no shared barrier) so one block's LDS phase overlaps the other's
// VALU phase. x: LDS-staged bf16 in fragment order; z: registers only
// (transposed-MFMA chain); P partials: bf16 pairs in ws, 1 barrier / 8 steps.
__global__ void __launch_bounds__(256, 2)
snn_l1_kernel(const float* __restrict__ x, const float* __restrict__ w1,
              const float* __restrict__ w2, u16* __restrict__ g2p,
              float* __restrict__ out)
{
    const int tid  = threadIdx.x;
    const int lane = tid & 63;
    const int wv   = tid >> 6;               // 4 waves; wave owns 16 hid
    const int hi   = lane >> 4;
    const int l15  = lane & 15;              // batch row within tile
    const int tile = blockIdx.x & 127;       // quarters of a tile: same XCD
    const int q    = blockIdx.x >> 7;        // hid quarter
    const int row0 = tile * 16;
    const int hbase = q * 64 + wv * 16;      // this wave's 16 hid

    // x frags: [buf][step][frag(2)][512 bf16] -> 16B/lane stride-1 reads
    __shared__ __attribute__((aligned(16))) u16 xl[2][CH * 2 * 512];     // 32 KB
    // P partials: [buf][step][wave][lane*2 u32] (bf16x4 per lane)
    __shared__ __attribute__((aligned(16))) u32 ws[2][CH][4][128];       // 16 KB
    __shared__ float sacc;
    if (tid == 0) sacc = 0.f;

    const f32x4 zf = {0.f, 0.f, 0.f, 0.f};
    const float dt_tau = (float)(0.001 * (1.0 / 0.006));       // 1/6
    const float decay  = (float)(1.0 - 0.001 * (1.0 / 0.006)); // 5/6

    // W1 as MFMA A-frags: A[n=hid][k=in]; lane: n = l15, k = 32kh + 8hi + i.
    bf16x8 w1f[2];
#pragma unroll
    for (int kh = 0; kh < 2; ++kh) {
        const float* src = &w1[(hbase + l15) * IN_F + kh * 32 + hi * 8];
        w1f[kh] = pack8(*(const float4*)src, *(const float4*)(src + 4));
    }
    // W2 as layer-2 B-frag, K=32 half-zero (slots i<4 <-> hid hbase+4hi+i).
    bf16x8 w2f;
#pragma unroll
    for (int i = 0; i < 8; ++i)
        w2f[i] = (i < 4) ? (short)f2bf(w2[l15 * HID + hbase + 4 * hi + i])
                         : (short)0;

    // ---- x staging map: 1024 16B-units per chunk, 4 per thread ----
    // unit u: s = u>>7; r7 = u&127: f = r7>>6, chi = (r7>>4)&3, cl = r7&15
    // holds bf16 of x[t0+s][row0+cl][32f + 8*chi .. +8]
    const size_t cstride = (size_t)CH * BATCH * IN_F;
    const float* gp[4];
    int wofs[4];
#pragma unroll
    for (int j = 0; j < 4; ++j) {
        const int u  = tid + 256 * j;
        const int s  = u >> 7, r7 = u & 127;
        const int f  = r7 >> 6, chi = (r7 >> 4) & 3, cl = r7 & 15;
        wofs[j] = (s * 2 + f) * 512 + (chi * 16 + cl) * 8;   // u16 index
        gp[j]   = x + ((size_t)s * BATCH + row0 + cl) * IN_F + f * 32 + chi * 8;
    }
    // prologue: chunk 0 -> LDS; chunk 1 -> regs (T14 split); gp -> chunk 2
    float4 ra[4], rb[4];
#pragma unroll
    for (int j = 0; j < 4; ++j) {
        ra[j] = *(const float4*)gp[j];
        rb[j] = *(const float4*)(gp[j] + 4);
        *(bf16x8*)&xl[0][wofs[j]] = pack8(ra[j], rb[j]);
    }
#pragma unroll
    for (int j = 0; j < 4; ++j) {
        ra[j] = *(const float4*)(gp[j] + cstride);
        rb[j] = *(const float4*)(gp[j] + cstride + 4);
        gp[j] += 2 * cstride;
    }

    f32x4 v1 = zf, i1 = zf;
    int wcnt = 0;
    __syncthreads();

    for (int c = 0; c < NCH; ++c) {
        const int cb = c & 1;
        const u16* xb = &xl[cb][0];

        // stage chunk c+1 from regs (dead buffer); issue loads for c+2
        if (c + 1 < NCH) {
#pragma unroll
            for (int j = 0; j < 4; ++j)
                *(bf16x8*)&xl[cb ^ 1][wofs[j]] = pack8(ra[j], rb[j]);
        }
        if (c + 2 < NCH) {
#pragma unroll
            for (int j = 0; j < 4; ++j) {
                ra[j] = *(const float4*)gp[j];
                rb[j] = *(const float4*)(gp[j] + 4);
                gp[j] += cstride;
            }
        }

#pragma unroll
        for (int s = 0; s < CH; ++s) {
            // stride-1, conflict-free 16B reads (shared x, own hid weights)
            const bf16x8 xf0 = *(const bf16x8*)&xb[(s * 2 + 0) * 512 + lane * 8];
            const bf16x8 xf1 = *(const bf16x8*)&xb[(s * 2 + 1) * 512 + lane * 8];

            // layer 1 (transposed): lane holds rows n = 4hi+r, col m = l15
            f32x4 g1 = __builtin_amdgcn_mfma_f32_16x16x32_bf16(w1f[0], xf0, zf, 0, 0, 0);
            g1 = __builtin_amdgcn_mfma_f32_16x16x32_bf16(w1f[1], xf1, g1, 0, 0, 0);

            // LIF: 4 hid of row l15; z stays in-lane
            const f32x4 vd = v1 + dt_tau * (i1 - v1);
            bool sp[4];
#pragma unroll
            for (int r = 0; r < 4; ++r) {
                sp[r] = vd[r] > 1.0f;
                v1[r] = sp[r] ? 0.f : vd[r];
                wcnt += __popcll(__ballot(sp[r]));
            }
            i1 = i1 * decay + g1;

            union { u32 u[4]; bf16x8 v; } zz;
            zz.u[0] = (sp[0] ? 0x3F80u : 0u) | (sp[1] ? 0x3F800000u : 0u);
            zz.u[1] = (sp[2] ? 0x3F80u : 0u) | (sp[3] ? 0x3F800000u : 0u);
            zz.u[2] = 0u; zz.u[3] = 0u;

            // layer-2 partial over this wave's 16 hid (K=32 half-zero)
            const f32x4 p = __builtin_amdgcn_mfma_f32_16x16x32_bf16(zz.v, w2f, zf, 0, 0, 0);
            uint2 pw;
            pw.x = (u32)f2bf(p[0]) | ((u32)f2bf(p[1]) << 16);
            pw.y = (u32)f2bf(p[2]) | ((u32)f2bf(p[3]) << 16);
            *(uint2*)&ws[cb][s][wv][lane * 2] = pw;
        }

        __syncthreads();   // one barrier per 8 steps (intra-block only)

        // reduce: wave wv sums 4 waves' partials for steps 2wv, 2wv+1;
        // next chunk's producers write ws[cb^1] -> no race (see R10 proof).
#pragma unroll
        for (int q2 = 0; q2 < 2; ++q2) {
            const int s = wv * 2 + q2;
            f32x4 acc = zf;
#pragma unroll
            for (int w = 0; w < 4; ++w) {
                const uint2 pw = *(const uint2*)&ws[cb][s][w][lane * 2];
                acc[0] += __uint_as_float(pw.x << 16);
                acc[1] += __uint_as_float(pw.x & 0xFFFF0000u);
                acc[2] += __uint_as_float(pw.y << 16);
                acc[3] += __uint_as_float(pw.y & 0xFFFF0000u);
            }
            const int t = c * CH + s;
            u16* dst = g2p + (size_t)q * (T_STEPS * SLAB)
                     + (size_t)t * SLAB + (row0 + 4 * hi) * OUT_F + l15;
#pragma unroll
            for (int r = 0; r < 4; ++r) dst[r * OUT_F] = f2bf(acc[r]);
        }
    }

    // spikes: wcnt is wave-uniform -> one LDS atomic per wave, one global atomic
    if (lane == 0) atomicAdd(&sacc, (float)wcnt);
    __syncthreads();
    if (tid == 0) atomicAdd(&out[BATCH * OUT_F], sacc * (1.0f / BATCH));
}

// Kernel 2: LI recurrence + max over t; one thread per (row, out) chain;
// sums the 4 quarter-slabs.
__global__ void __launch_bounds__(256)
snn_li_kernel(const u16* __restrict__ g2p, float* __restrict__ out)
{
    const int gid = blockIdx.x * 256 + threadIdx.x;    // 0..32767
    const u16* p0 = g2p + gid;
    const u16* p1 = p0 + (size_t)T_STEPS * SLAB;
    const u16* p2 = p1 + (size_t)T_STEPS * SLAB;
    const u16* p3 = p2 + (size_t)T_STEPS * SLAB;
    const float dt_tau = (float)(0.001 * (1.0 / 0.006));
    const float decay  = (float)(1.0 - 0.001 * (1.0 / 0.006));
    float v2 = 0.f, i2 = 0.f, ymax = -1e30f;
#pragma unroll 8
    for (int t = 0; t < T_STEPS; ++t) {
        const size_t o = (size_t)t * SLAB;
        const float g = (bf2f(p0[o]) + bf2f(p1[o])) + (bf2f(p2[o]) + bf2f(p3[o]));
        v2 = fmaf(dt_tau, i2 - v2, v2);   // uses old i2, matches reference
        ymax = fmaxf(ymax, v2);
        i2 = i2 * decay + g;
    }
    out[gid] = ymax;
}

extern "C" void kernel_launch(void* const* d_in, const int* in_sizes, int n_in,
                              void* d_out, int out_size, void* d_ws, size_t ws_size,
                              hipStream_t stream) {
    const float* x  = (const float*)d_in[0];
    const float* w1 = (const float*)d_in[1];
    const float* w2 = (const float*)d_in[2];
    float* out = (float*)d_out;
    u16* g2p = (u16*)d_ws;   // 4 quarters x 128 t x 32768 bf16 = 32 MB

    hipLaunchKernelGGL(snn_init_kernel, dim3(1), dim3(64), 0, stream, out);
    hipLaunchKernelGGL(snn_l1_kernel, dim3(512), dim3(256), 0, stream,
                       x, w1, w2, g2p, out);
    hipLaunchKernelGGL(snn_li_kernel, dim3(BATCH * OUT_F / 256), dim3(256), 0,
                       stream, g2p, out);
}

// Round 12
// 56.122 us; speedup vs baseline: 1.2246x; 1.2246x over previous
//
#include <hip/hip_runtime.h>
#include <hip/hip_bf16.h>

#define T_STEPS 128
#define BATCH   2048
#define IN_F    64
#define HID     256
#define OUT_F   16
#define CH      8                  // timesteps per chunk (= 8 waves, 1 g2-step each)
#define NCH     (T_STEPS / CH)     // 16 chunks
#define SLAB    (BATCH * OUT_F)

typedef __attribute__((ext_vector_type(8))) short bf16x8;
typedef __attribute__((ext_vector_type(4))) float f32x4;
typedef unsigned short u16;
typedef unsigned int   u32;

__device__ __forceinline__ u16 f2bf(float f) {      // RNE via HW cvt (pk-fusable)
    union { __hip_bfloat16 h; u16 u; } cv;
    cv.h = __float2bfloat16(f);
    return cv.u;
}
__device__ __forceinline__ float bf2f(u16 h) {
    return __uint_as_float(((u32)h) << 16);
}
__device__ __forceinline__ bf16x8 pack8(float4 a, float4 b) {
    bf16x8 r;
    r[0] = (short)f2bf(a.x); r[1] = (short)f2bf(a.y);
    r[2] = (short)f2bf(a.z); r[3] = (short)f2bf(a.w);
    r[4] = (short)f2bf(b.x); r[5] = (short)f2bf(b.y);
    r[6] = (short)f2bf(b.z); r[7] = (short)f2bf(b.w);
    return r;
}

// LDS-only barrier: drains lgkmcnt (LDS visibility) but NOT vmcnt, so global
// prefetch loads / slab stores never sit on the barrier critical path.
// rule #18: sched_barrier(0) after inline-asm waitcnt.
__device__ __forceinline__ void lds_barrier() {
    __builtin_amdgcn_sched_barrier(0);
    asm volatile("s_waitcnt lgkmcnt(0)" ::: "memory");
    __builtin_amdgcn_sched_barrier(0);
    __builtin_amdgcn_s_barrier();
    __builtin_amdgcn_sched_barrier(0);
}

// Zero the spikes_mean accumulator (d_out not re-poisoned between replays).
__global__ void snn_init_kernel(float* __restrict__ out) {
    if (threadIdx.x == 0 && blockIdx.x == 0) out[BATCH * OUT_F] = 0.0f;
}

// Kernel 1: block = 16 rows x 128 hid, 8 waves (wave = 16 hid). Transposed
// layer-1 (z C-layout is hid-consecutive per lane) -> one b64 z-write/step in
// A-frag fragment order; per chunk each wave computes one step's FULL-K g2
// (4 ds_read_b128 + 4 MFMA) and stores the bf16 slab directly. Raw lgkm-only
// barriers, 2 per chunk.
__global__ void __launch_bounds__(512, 2)
snn_l1_kernel(const float* __restrict__ x, const float* __restrict__ w1,
              const float* __restrict__ w2, u16* __restrict__ g2p,
              float* __restrict__ out)
{
    const int tid  = threadIdx.x;
    const int lane = tid & 63;
    const int wv   = tid >> 6;               // 8 waves; wave owns 16 hid
    const int hi   = lane >> 4;
    const int l15  = lane & 15;              // batch row within tile
    const int tile = blockIdx.x & 127;       // halves of a tile: same XCD
    const int half = blockIdx.x >> 7;
    const int row0 = tile * 16;
    const int hbase = half * 128 + wv * 16;  // this wave's 16 hid

    // x frags: [buf][step][frag(2)][512 bf16] -> 16B/lane stride-1 reads
    __shared__ __attribute__((aligned(16))) u16 xl[2][CH * 2 * 512];   // 32 KB
    // z in A-frag order: [step][kt(4)][512 bf16]; single-buffered (see races)
    __shared__ __attribute__((aligned(16))) u16 zb[CH * 4 * 512];      // 32 KB
    __shared__ float sacc;
    if (tid == 0) sacc = 0.f;

    const f32x4 zf = {0.f, 0.f, 0.f, 0.f};
    const float dt_tau = (float)(0.001 * (1.0 / 0.006));       // 1/6
    const float decay  = (float)(1.0 - 0.001 * (1.0 / 0.006)); // 5/6

    // W1 as MFMA A-frags (transposed L1): A[m=hid][k=in]; lane m = l15.
    bf16x8 w1f[2];
#pragma unroll
    for (int kh = 0; kh < 2; ++kh) {
        const float* src = &w1[(hbase + l15) * IN_F + kh * 32 + hi * 8];
        w1f[kh] = pack8(*(const float4*)src, *(const float4*)(src + 4));
    }
    // W2 B-frags, full local K=128: col = o = l15, slice kt: k-slot 8hi+i
    // <-> hid half*128 + 32kt + 8hi + i (natural order: the z fragment-order
    // store below lands z in exactly this k-order — derivation in comments).
    bf16x8 w2f[4];
#pragma unroll
    for (int kt = 0; kt < 4; ++kt) {
        const int k0 = half * 128 + kt * 32 + hi * 8;
        w2f[kt] = pack8(*(const float4*)&w2[l15 * HID + k0],
                        *(const float4*)&w2[l15 * HID + k0 + 4]);
    }

    // ---- x staging map: 1024 16B-units per chunk, 2 per thread ----
    const size_t cstride = (size_t)CH * BATCH * IN_F;
    const float* gp[2];
    int wofs[2];
#pragma unroll
    for (int j = 0; j < 2; ++j) {
        const int u  = tid + 512 * j;
        const int s  = u >> 7, r7 = u & 127;
        const int f  = r7 >> 6, chi = (r7 >> 4) & 3, cl = r7 & 15;
        wofs[j] = (s * 2 + f) * 512 + (chi * 16 + cl) * 8;   // u16 index
        gp[j]   = x + ((size_t)s * BATCH + row0 + cl) * IN_F + f * 32 + chi * 8;
    }
    // prologue: chunk 0 -> LDS; chunk 1 -> regs; gp -> chunk 2
    float4 ra[2], rb[2];
#pragma unroll
    for (int j = 0; j < 2; ++j) {
        ra[j] = *(const float4*)gp[j];
        rb[j] = *(const float4*)(gp[j] + 4);
        *(bf16x8*)&xl[0][wofs[j]] = pack8(ra[j], rb[j]);
    }
#pragma unroll
    for (int j = 0; j < 2; ++j) {
        ra[j] = *(const float4*)(gp[j] + cstride);
        rb[j] = *(const float4*)(gp[j] + cstride + 4);
        gp[j] += 2 * cstride;
    }

    // z-write address (fragment order). Writer lane (hi,l15) of wave wv holds
    // z[row=l15][hidL = 16wv + 4hi + r], r=0..3 consecutive -> one b64.
    // Dest slice kt=wv>>1; reader lane hiR = 2(wv&1)+(hi>>1), slot i = 4(hi&1)+r
    // -> reader slot k = 8hiR+i == hidL - 32kt (natural k-order, matches w2f).
    // XOR keys spread the 4 same-bank writer lanes {l15>>3, hi>>1} by
    // {0,8,16,24} banks; keys are reader-computable (writer l15 == reader l15,
    // writer hi>>1 == reader hiR&1), and >=16B-granular so b128 reads stay
    // aligned and conflict-free.
    const int zwkey = ((l15 >> 3) << 5) | (((hi >> 1) & 1) << 4);
    const int zwofs = (wv >> 1) * 512
                    + (((((wv & 1) * 2 + (hi >> 1)) * 16 + l15) * 8 + (hi & 1) * 4)
                       ^ zwkey);
    const int zrkey = ((l15 >> 3) << 5) | ((hi & 1) << 4);
    const int zrofs = ((hi * 16 + l15) * 8) ^ zrkey;

    f32x4 v1 = zf, i1 = zf;
    int wcnt = 0;
    lds_barrier();

    for (int c = 0; c < NCH; ++c) {
        const int cb = c & 1;
        const u16* xb = &xl[cb][0];

        // ---- phase A/B: 8 steps of {x-frag read, g1 MFMA, LIF, z b64 write} ----
#pragma unroll
        for (int s = 0; s < CH; ++s) {
            const bf16x8 xf0 = *(const bf16x8*)&xb[(s * 2 + 0) * 512 + lane * 8];
            const bf16x8 xf1 = *(const bf16x8*)&xb[(s * 2 + 1) * 512 + lane * 8];

            f32x4 g1 = __builtin_amdgcn_mfma_f32_16x16x32_bf16(w1f[0], xf0, zf, 0, 0, 0);
            g1 = __builtin_amdgcn_mfma_f32_16x16x32_bf16(w1f[1], xf1, g1, 0, 0, 0);

            const f32x4 vd = v1 + dt_tau * (i1 - v1);
            bool sp[4];
#pragma unroll
            for (int r = 0; r < 4; ++r) {
                sp[r] = vd[r] > 1.0f;
                v1[r] = sp[r] ? 0.f : vd[r];
                wcnt += __popcll(__ballot(sp[r]));
            }
            i1 = i1 * decay + g1;

            uint2 zi;
            zi.x = (sp[0] ? 0x3F80u : 0u) | (sp[1] ? 0x3F800000u : 0u);
            zi.y = (sp[2] ? 0x3F80u : 0u) | (sp[3] ? 0x3F800000u : 0u);
            *(uint2*)&zb[s * 2048 + zwofs] = zi;   // one swizzled b64 per step
        }

        lds_barrier();   // bar1: z(chunk) visible; xl[cb] reads drained

        // ---- phase C ----
        // stage chunk c+1 into the dead xl buffer (LDS writes -> drained at bar2)
        if (c + 1 < NCH) {
#pragma unroll
            for (int j = 0; j < 2; ++j)
                *(bf16x8*)&xl[cb ^ 1][wofs[j]] = pack8(ra[j], rb[j]);
        }
        // issue global loads for chunk c+2 (consumed next chunk's phase C --
        // a full chunk (~>2000 cyc) later; never drained at barriers)
        if (c + 2 < NCH) {
#pragma unroll
            for (int j = 0; j < 2; ++j) {
                ra[j] = *(const float4*)gp[j];
                rb[j] = *(const float4*)(gp[j] + 4);
                gp[j] += cstride;
            }
        }
        // full-K g2 for step s = wv: 4 conflict-free b128 reads + 4 MFMAs
        {
            const u16* zr = &zb[wv * 2048];
            f32x4 g2 = zf;
#pragma unroll
            for (int kt = 0; kt < 4; ++kt) {
                const bf16x8 zfr = *(const bf16x8*)&zr[kt * 512 + zrofs];
                g2 = __builtin_amdgcn_mfma_f32_16x16x32_bf16(zfr, w2f[kt], g2, 0, 0, 0);
            }
            // D[m=row][o]: lane holds rows 4hi+r, col o = l15 (slab store,
            // never waited on)
            u16* dst = g2p + (size_t)half * (T_STEPS * SLAB)
                     + (size_t)(c * CH + wv) * SLAB + (row0 + 4 * hi) * OUT_F + l15;
#pragma unroll
            for (int r = 0; r < 4; ++r) dst[r * OUT_F] = f2bf(g2[r]);
        }

        lds_barrier();   // bar2: xl[cb^1] visible; zb reads drained
        // races: zb written A(c), read C(c) [bar1 between]; rewritten A(c+1)
        // [bar2 drains C(c) reads]. xl[cb^1] written C(c), read A(c+1) [bar2].
        // xl[cb] read A(c) [drained bar1(c)], rewritten C(c+1).
    }

    // spikes: wcnt is wave-uniform -> one LDS atomic per wave, one global atomic
    if (lane == 0) atomicAdd(&sacc, (float)wcnt);
    __syncthreads();
    if (tid == 0) atomicAdd(&out[BATCH * OUT_F], sacc * (1.0f / BATCH));
}

// Kernel 2: LI recurrence + max over t; one thread per (row, out) chain;
// sums the 2 half-slabs.
__global__ void __launch_bounds__(256)
snn_li_kernel(const u16* __restrict__ g2p, float* __restrict__ out)
{
    const int gid = blockIdx.x * 256 + threadIdx.x;    // 0..32767
    const u16* p0 = g2p + gid;
    const u16* p1 = p0 + (size_t)T_STEPS * SLAB;
    const float dt_tau = (float)(0.001 * (1.0 / 0.006));
    const float decay  = (float)(1.0 - 0.001 * (1.0 / 0.006));
    float v2 = 0.f, i2 = 0.f, ymax = -1e30f;
#pragma unroll 8
    for (int t = 0; t < T_STEPS; ++t) {
        const size_t o = (size_t)t * SLAB;
        const float g = bf2f(p0[o]) + bf2f(p1[o]);
        v2 = fmaf(dt_tau, i2 - v2, v2);   // uses old i2, matches reference
        ymax = fmaxf(ymax, v2);
        i2 = i2 * decay + g;
    }
    out[gid] = ymax;
}

extern "C" void kernel_launch(void* const* d_in, const int* in_sizes, int n_in,
                              void* d_out, int out_size, void* d_ws, size_t ws_size,
                              hipStream_t stream) {
    const float* x  = (const float*)d_in[0];
    const float* w1 = (const float*)d_in[1];
    const float* w2 = (const float*)d_in[2];
    float* out = (float*)d_out;
    u16* g2p = (u16*)d_ws;   // 2 halves x 128 t x 32768 bf16 = 16 MB

    hipLaunchKernelGGL(snn_init_kernel, dim3(1), dim3(64), 0, stream, out);
    hipLaunchKernelGGL(snn_l1_kernel, dim3(256), dim3(512), 0, stream,
                       x, w1, w2, g2p, out);
    hipLaunchKernelGGL(snn_li_kernel, dim3(BATCH * OUT_F / 256), dim3(256), 0,
                       stream, g2p, out);
}

// Round 13
// 53.913 us; speedup vs baseline: 1.2748x; 1.0410x over previous
//
#include <hip/hip_runtime.h>
#include <hip/hip_bf16.h>

#define T_STEPS 128
#define BATCH   2048
#define IN_F    64
#define HID     256
#define OUT_F   16
#define CH      8                  // timesteps per chunk (= 8 waves, 1 g2-step each)
#define NCH     (T_STEPS / CH)     // 16 chunks
#define SLAB    (BATCH * OUT_F)

typedef __attribute__((ext_vector_type(8))) short bf16x8;
typedef __attribute__((ext_vector_type(4))) float f32x4;
typedef unsigned short u16;
typedef unsigned int   u32;

__device__ __forceinline__ u16 f2bf(float f) {      // RNE via HW cvt (pk-fusable)
    union { __hip_bfloat16 h; u16 u; } cv;
    cv.h = __float2bfloat16(f);
    return cv.u;
}
__device__ __forceinline__ float bf2f(u16 h) {
    return __uint_as_float(((u32)h) << 16);
}
__device__ __forceinline__ bf16x8 pack8(float4 a, float4 b) {
    bf16x8 r;
    r[0] = (short)f2bf(a.x); r[1] = (short)f2bf(a.y);
    r[2] = (short)f2bf(a.z); r[3] = (short)f2bf(a.w);
    r[4] = (short)f2bf(b.x); r[5] = (short)f2bf(b.y);
    r[6] = (short)f2bf(b.z); r[7] = (short)f2bf(b.w);
    return r;
}

// LDS-only barrier: drains lgkmcnt (LDS visibility) but NOT vmcnt, so global
// prefetch loads / slab stores never sit on the barrier critical path.
__device__ __forceinline__ void lds_barrier() {
    __builtin_amdgcn_sched_barrier(0);
    asm volatile("s_waitcnt lgkmcnt(0)" ::: "memory");
    __builtin_amdgcn_sched_barrier(0);
    __builtin_amdgcn_s_barrier();
    __builtin_amdgcn_sched_barrier(0);
}

// Zero the spikes_mean accumulator (d_out not re-poisoned between replays).
__global__ void snn_init_kernel(float* __restrict__ out) {
    if (threadIdx.x == 0 && blockIdx.x == 0) out[BATCH * OUT_F] = 0.0f;
}

// Kernel 1: block = 16 rows x 128 hid, 8 waves (wave = 16 hid). Transposed
// layer-1; z packed in registers during the 8-step compute (no ds_write in
// the pipelined region), written as 8 b64 at phase end; distance-2 software
// pipeline on the x-frag ds_reads; ONE lgkm-only barrier per chunk.
__global__ void __launch_bounds__(512, 2)
snn_l1_kernel(const float* __restrict__ x, const float* __restrict__ w1,
              const float* __restrict__ w2, u16* __restrict__ g2p,
              float* __restrict__ out)
{
    const int tid  = threadIdx.x;
    const int lane = tid & 63;
    const int wv   = tid >> 6;               // 8 waves; wave owns 16 hid
    const int hi   = lane >> 4;
    const int l15  = lane & 15;              // batch row within tile
    const int tile = blockIdx.x & 127;       // halves of a tile: same XCD
    const int half = blockIdx.x >> 7;
    const int row0 = tile * 16;
    const int hbase = half * 128 + wv * 16;  // this wave's 16 hid

    // x frags: [buf][step][frag(2)][512 bf16] -> 16B/lane stride-1 reads
    __shared__ __attribute__((aligned(16))) u16 xl[2][CH * 2 * 512];   // 32 KB
    // z in A-frag order: [buf][step][kt(4)][512 bf16] (double-buffered)
    __shared__ __attribute__((aligned(16))) u16 zb[2][CH * 4 * 512];   // 64 KB
    __shared__ float sacc;
    if (tid == 0) sacc = 0.f;

    const f32x4 zf = {0.f, 0.f, 0.f, 0.f};
    const float dt_tau = (float)(0.001 * (1.0 / 0.006));       // 1/6
    const float decay  = (float)(1.0 - 0.001 * (1.0 / 0.006)); // 5/6

    // W1 as MFMA A-frags (transposed L1): A[m=hid][k=in]; lane m = l15.
    bf16x8 w1f[2];
#pragma unroll
    for (int kh = 0; kh < 2; ++kh) {
        const float* src = &w1[(hbase + l15) * IN_F + kh * 32 + hi * 8];
        w1f[kh] = pack8(*(const float4*)src, *(const float4*)(src + 4));
    }
    // W2 B-frags, full local K=128 (k-order matches the z fragment store).
    bf16x8 w2f[4];
#pragma unroll
    for (int kt = 0; kt < 4; ++kt) {
        const int k0 = half * 128 + kt * 32 + hi * 8;
        w2f[kt] = pack8(*(const float4*)&w2[l15 * HID + k0],
                        *(const float4*)&w2[l15 * HID + k0 + 4]);
    }

    // ---- x staging map: 1024 16B-units per chunk, 2 per thread ----
    const size_t cstride = (size_t)CH * BATCH * IN_F;
    const float* gp[2];
    int wofs[2];
#pragma unroll
    for (int j = 0; j < 2; ++j) {
        const int u  = tid + 512 * j;
        const int s  = u >> 7, r7 = u & 127;
        const int f  = r7 >> 6, chi = (r7 >> 4) & 3, cl = r7 & 15;
        wofs[j] = (s * 2 + f) * 512 + (chi * 16 + cl) * 8;   // u16 index
        gp[j]   = x + ((size_t)s * BATCH + row0 + cl) * IN_F + f * 32 + chi * 8;
    }
    // prologue: chunk 0 -> LDS; chunk 1 -> regs; gp -> chunk 2
    float4 ra[2], rb[2];
#pragma unroll
    for (int j = 0; j < 2; ++j) {
        ra[j] = *(const float4*)gp[j];
        rb[j] = *(const float4*)(gp[j] + 4);
        *(bf16x8*)&xl[0][wofs[j]] = pack8(ra[j], rb[j]);
    }
#pragma unroll
    for (int j = 0; j < 2; ++j) {
        ra[j] = *(const float4*)(gp[j] + cstride);
        rb[j] = *(const float4*)(gp[j] + cstride + 4);
        gp[j] += 2 * cstride;
    }

    // z-write / z-read swizzled addresses (verified R12, absmax 0.0488)
    const int zwkey = ((l15 >> 3) << 5) | (((hi >> 1) & 1) << 4);
    const int zwofs = (wv >> 1) * 512
                    + (((((wv & 1) * 2 + (hi >> 1)) * 16 + l15) * 8 + (hi & 1) * 4)
                       ^ zwkey);
    const int zrkey = ((l15 >> 3) << 5) | ((hi & 1) << 4);
    const int zrofs = ((hi * 16 + l15) * 8) ^ zrkey;

    f32x4 v1 = zf, i1 = zf;
    int wcnt = 0;
    lds_barrier();

    for (int c = 0; c < NCH; ++c) {
        const int cb = c & 1;
        const u16* xb = &xl[cb][0];
        u16* zw = &zb[cb][0];

        // ---- phase A: distance-2 pipelined reads; compute is LDS-write-free ----
        bf16x8 xfa[CH], xfb[CH];
#pragma unroll
        for (int s = 0; s < 2; ++s) {
            xfa[s] = *(const bf16x8*)&xb[(s * 2 + 0) * 512 + lane * 8];
            xfb[s] = *(const bf16x8*)&xb[(s * 2 + 1) * 512 + lane * 8];
        }
        uint2 zi[CH];
#pragma unroll
        for (int s = 0; s < CH; ++s) {
            if (s + 2 < CH) {      // issue reads for step s+2 before compute s
                xfa[s + 2] = *(const bf16x8*)&xb[((s + 2) * 2 + 0) * 512 + lane * 8];
                xfb[s + 2] = *(const bf16x8*)&xb[((s + 2) * 2 + 1) * 512 + lane * 8];
            }
            f32x4 g1 = __builtin_amdgcn_mfma_f32_16x16x32_bf16(w1f[0], xfa[s], zf, 0, 0, 0);
            g1 = __builtin_amdgcn_mfma_f32_16x16x32_bf16(w1f[1], xfb[s], g1, 0, 0, 0);

            const f32x4 vd = v1 + dt_tau * (i1 - v1);
            bool sp[4];
#pragma unroll
            for (int r = 0; r < 4; ++r) {
                sp[r] = vd[r] > 1.0f;
                v1[r] = sp[r] ? 0.f : vd[r];
                wcnt += __popcll(__ballot(sp[r]));
            }
            i1 = i1 * decay + g1;

            zi[s].x = (sp[0] ? 0x3F80u : 0u) | (sp[1] ? 0x3F800000u : 0u);
            zi[s].y = (sp[2] ? 0x3F80u : 0u) | (sp[3] ? 0x3F800000u : 0u);
        }
        // deferred z-writes (one swizzled b64 per step)
#pragma unroll
        for (int s = 0; s < CH; ++s)
            *(uint2*)&zw[s * 2048 + zwofs] = zi[s];
        // stage chunk c+1 into the dead xl buffer
        if (c + 1 < NCH) {
#pragma unroll
            for (int j = 0; j < 2; ++j)
                *(bf16x8*)&xl[cb ^ 1][wofs[j]] = pack8(ra[j], rb[j]);
        }

        lds_barrier();   // the ONLY barrier per chunk

        // ---- phase C (barrier-free) ----
        if (c + 2 < NCH) {   // issue global loads for chunk c+2 first
#pragma unroll
            for (int j = 0; j < 2; ++j) {
                ra[j] = *(const float4*)gp[j];
                rb[j] = *(const float4*)(gp[j] + 4);
                gp[j] += cstride;
            }
        }
        // full-K g2 for step s = wv: 4 conflict-free b128 reads + 4 MFMAs
        {
            const u16* zr = &zb[cb][wv * 2048];
            f32x4 g2 = zf;
#pragma unroll
            for (int kt = 0; kt < 4; ++kt) {
                const bf16x8 zfr = *(const bf16x8*)&zr[kt * 512 + zrofs];
                g2 = __builtin_amdgcn_mfma_f32_16x16x32_bf16(zfr, w2f[kt], g2, 0, 0, 0);
            }
            u16* dst = g2p + (size_t)half * (T_STEPS * SLAB)
                     + (size_t)(c * CH + wv) * SLAB + (row0 + 4 * hi) * OUT_F + l15;
#pragma unroll
            for (int r = 0; r < 4; ++r) dst[r * OUT_F] = f2bf(g2[r]);
        }
        // race audit (one bar/chunk): xl[cb] reads drain at BAR(c), rewritten
        // in A(c+2) which is past BAR(c+1); zb[cb] written A(c), read C(c)
        // after BAR(c), rewritten A(c+2); a wave racing ahead into A(c+1)
        // writes only xl[cb]/zb[cb^1] -- disjoint from laggards in C(c).
    }

    // spikes: wcnt is wave-uniform -> one LDS atomic per wave, one global atomic
    if (lane == 0) atomicAdd(&sacc, (float)wcnt);
    __syncthreads();
    if (tid == 0) atomicAdd(&out[BATCH * OUT_F], sacc * (1.0f / BATCH));
}

// Kernel 2: LI recurrence + max over t; one thread per (row, out) chain;
// sums the 2 half-slabs.
__global__ void __launch_bounds__(256)
snn_li_kernel(const u16* __restrict__ g2p, float* __restrict__ out)
{
    const int gid = blockIdx.x * 256 + threadIdx.x;    // 0..32767
    const u16* p0 = g2p + gid;
    const u16* p1 = p0 + (size_t)T_STEPS * SLAB;
    const float dt_tau = (float)(0.001 * (1.0 / 0.006));
    const float decay  = (float)(1.0 - 0.001 * (1.0 / 0.006));
    float v2 = 0.f, i2 = 0.f, ymax = -1e30f;
#pragma unroll 8
    for (int t = 0; t < T_STEPS; ++t) {
        const size_t o = (size_t)t * SLAB;
        const float g = bf2f(p0[o]) + bf2f(p1[o]);
        v2 = fmaf(dt_tau, i2 - v2, v2);   // uses old i2, matches reference
        ymax = fmaxf(ymax, v2);
        i2 = i2 * decay + g;
    }
    out[gid] = ymax;
}

extern "C" void kernel_launch(void* const* d_in, const int* in_sizes, int n_in,
                              void* d_out, int out_size, void* d_ws, size_t ws_size,
                              hipStream_t stream) {
    const float* x  = (const float*)d_in[0];
    const float* w1 = (const float*)d_in[1];
    const float* w2 = (const float*)d_in[2];
    float* out = (float*)d_out;
    u16* g2p = (u16*)d_ws;   // 2 halves x 128 t x 32768 bf16 = 16 MB

    hipLaunchKernelGGL(snn_init_kernel, dim3(1), dim3(64), 0, stream, out);
    hipLaunchKernelGGL(snn_l1_kernel, dim3(256), dim3(512), 0, stream,
                       x, w1, w2, g2p, out);
    hipLaunchKernelGGL(snn_li_kernel, dim3(BATCH * OUT_F / 256), dim3(256), 0,
                       stream, g2p, out);
}

// Round 14
// 44.546 us; speedup vs baseline: 1.5429x; 1.2103x over previous
//
#include <hip/hip_runtime.h>
#include <hip/hip_bf16.h>

#define T_STEPS 128
#define BATCH   2048
#define IN_F    64
#define HID     256
#define OUT_F   16
#define CH      8                  // timesteps per chunk (= 8 waves, 1 g2-step each)
#define NCH     (T_STEPS / CH)     // 16 chunks
#define SLAB    (BATCH * OUT_F)
#define SPART_OFS (32u * 1024u * 1024u)   // byte offset of spike partials in d_ws

typedef __attribute__((ext_vector_type(8))) short bf16x8;
typedef __attribute__((ext_vector_type(4))) float f32x4;
typedef unsigned short u16;
typedef unsigned int   u32;

__device__ __forceinline__ u16 f2bf(float f) {      // RNE via HW cvt (pk-fusable)
    union { __hip_bfloat16 h; u16 u; } cv;
    cv.h = __float2bfloat16(f);
    return cv.u;
}
__device__ __forceinline__ float bf2f(u16 h) {
    return __uint_as_float(((u32)h) << 16);
}
__device__ __forceinline__ bf16x8 pack8(float4 a, float4 b) {
    bf16x8 r;
    r[0] = (short)f2bf(a.x); r[1] = (short)f2bf(a.y);
    r[2] = (short)f2bf(a.z); r[3] = (short)f2bf(a.w);
    r[4] = (short)f2bf(b.x); r[5] = (short)f2bf(b.y);
    r[6] = (short)f2bf(b.z); r[7] = (short)f2bf(b.w);
    return r;
}

// LDS-only barrier: drains lgkmcnt but NOT vmcnt (global prefetch loads /
// slab stores never sit on the barrier critical path).
__device__ __forceinline__ void lds_barrier() {
    __builtin_amdgcn_sched_barrier(0);
    asm volatile("s_waitcnt lgkmcnt(0)" ::: "memory");
    __builtin_amdgcn_sched_barrier(0);
    __builtin_amdgcn_s_barrier();
    __builtin_amdgcn_sched_barrier(0);
}

// Kernel 1: block = 16 rows x 128 hid, 8 waves (wave = 16 hid). Transposed
// layer-1; z packed in regs during compute, 8 deferred b64 writes; dist-3
// pipelined x-frag reads; ONE lgkm-only barrier per chunk; wave-parity phase
// stagger (even: A(c+1) then C(c); odd: C(c) then A(c+1)) + setprio on C's
// MFMA cluster. Spike counts: per-wave u32 partials, no atomics, no init.
__global__ void __launch_bounds__(512, 2)
snn_l1_kernel(const float* __restrict__ x, const float* __restrict__ w1,
              const float* __restrict__ w2, u16* __restrict__ g2p,
              u32* __restrict__ spart)
{
    const int tid  = threadIdx.x;
    const int lane = tid & 63;
    const int wv   = tid >> 6;               // 8 waves; wave owns 16 hid
    const int hi   = lane >> 4;
    const int l15  = lane & 15;              // batch row within tile
    const int tile = blockIdx.x & 127;       // halves of a tile: same XCD
    const int half = blockIdx.x >> 7;
    const int row0 = tile * 16;
    const int hbase = half * 128 + wv * 16;  // this wave's 16 hid

    __shared__ __attribute__((aligned(16))) u16 xl[2][CH * 2 * 512];   // 32 KB
    __shared__ __attribute__((aligned(16))) u16 zb[2][CH * 4 * 512];   // 64 KB

    const f32x4 zf = {0.f, 0.f, 0.f, 0.f};
    const float dt_tau = (float)(0.001 * (1.0 / 0.006));       // 1/6
    const float decay  = (float)(1.0 - 0.001 * (1.0 / 0.006)); // 5/6

    // W1 as MFMA A-frags (transposed L1): A[m=hid][k=in]; lane m = l15.
    bf16x8 w1f[2];
#pragma unroll
    for (int kh = 0; kh < 2; ++kh) {
        const float* src = &w1[(hbase + l15) * IN_F + kh * 32 + hi * 8];
        w1f[kh] = pack8(*(const float4*)src, *(const float4*)(src + 4));
    }
    // W2 B-frags, full local K=128 (k-order matches the z fragment store).
    bf16x8 w2f[4];
#pragma unroll
    for (int kt = 0; kt < 4; ++kt) {
        const int k0 = half * 128 + kt * 32 + hi * 8;
        w2f[kt] = pack8(*(const float4*)&w2[l15 * HID + k0],
                        *(const float4*)&w2[l15 * HID + k0 + 4]);
    }

    // ---- x staging map: 1024 16B-units per chunk, 2 per thread ----
    const size_t cstride = (size_t)CH * BATCH * IN_F;
    const float* gp[2];
    int wofs[2];
#pragma unroll
    for (int j = 0; j < 2; ++j) {
        const int u  = tid + 512 * j;
        const int s  = u >> 7, r7 = u & 127;
        const int f  = r7 >> 6, chi = (r7 >> 4) & 3, cl = r7 & 15;
        wofs[j] = (s * 2 + f) * 512 + (chi * 16 + cl) * 8;   // u16 index
        gp[j]   = x + ((size_t)s * BATCH + row0 + cl) * IN_F + f * 32 + chi * 8;
    }
    // prologue: chunk 0 -> xl[0]; chunk 1 -> regs; gp -> chunk 2
    float4 ra[2], rb[2];
#pragma unroll
    for (int j = 0; j < 2; ++j) {
        ra[j] = *(const float4*)gp[j];
        rb[j] = *(const float4*)(gp[j] + 4);
        *(bf16x8*)&xl[0][wofs[j]] = pack8(ra[j], rb[j]);
    }
#pragma unroll
    for (int j = 0; j < 2; ++j) {
        ra[j] = *(const float4*)(gp[j] + cstride);
        rb[j] = *(const float4*)(gp[j] + cstride + 4);
        gp[j] += 2 * cstride;
    }

    // z-write / z-read swizzled addresses (verified R12/R13, absmax 0.0488)
    const int zwkey = ((l15 >> 3) << 5) | (((hi >> 1) & 1) << 4);
    const int zwofs = (wv >> 1) * 512
                    + (((((wv & 1) * 2 + (hi >> 1)) * 16 + l15) * 8 + (hi & 1) * 4)
                       ^ zwkey);
    const int zrkey = ((l15 >> 3) << 5) | ((hi & 1) << 4);
    const int zrofs = ((hi * 16 + l15) * 8) ^ zrkey;

    f32x4 v1 = zf, i1 = zf;
    int wcnt = 0;

    // phase A(k): on entry regs hold chunk k+1. Stage them to xl[(k+1)&1],
    // issue loads for chunk k+2, compute 8 LIF steps from xl[k&1] with dist-3
    // pipelined reads, deferred z-writes to zb[k&1].
    auto phaseA = [&](int k) {
        const int kb = k & 1;
        const u16* xb = &xl[kb][0];
        u16* zw = &zb[kb][0];
        if (k + 1 < NCH) {
#pragma unroll
            for (int j = 0; j < 2; ++j)
                *(bf16x8*)&xl[kb ^ 1][wofs[j]] = pack8(ra[j], rb[j]);
        }
        if (k + 2 < NCH) {
#pragma unroll
            for (int j = 0; j < 2; ++j) {
                ra[j] = *(const float4*)gp[j];
                rb[j] = *(const float4*)(gp[j] + 4);
                gp[j] += cstride;
            }
        }
        bf16x8 xfa[CH], xfb[CH];
#pragma unroll
        for (int s = 0; s < 3; ++s) {
            xfa[s] = *(const bf16x8*)&xb[(s * 2 + 0) * 512 + lane * 8];
            xfb[s] = *(const bf16x8*)&xb[(s * 2 + 1) * 512 + lane * 8];
        }
        uint2 zi[CH];
#pragma unroll
        for (int s = 0; s < CH; ++s) {
            if (s + 3 < CH) {
                xfa[s + 3] = *(const bf16x8*)&xb[((s + 3) * 2 + 0) * 512 + lane * 8];
                xfb[s + 3] = *(const bf16x8*)&xb[((s + 3) * 2 + 1) * 512 + lane * 8];
            }
            f32x4 g1 = __builtin_amdgcn_mfma_f32_16x16x32_bf16(w1f[0], xfa[s], zf, 0, 0, 0);
            g1 = __builtin_amdgcn_mfma_f32_16x16x32_bf16(w1f[1], xfb[s], g1, 0, 0, 0);

            const f32x4 vd = v1 + dt_tau * (i1 - v1);
            bool sp[4];
#pragma unroll
            for (int r = 0; r < 4; ++r) {
                sp[r] = vd[r] > 1.0f;
                v1[r] = sp[r] ? 0.f : vd[r];
                wcnt += __popcll(__ballot(sp[r]));
            }
            i1 = i1 * decay + g1;
            zi[s].x = (sp[0] ? 0x3F80u : 0u) | (sp[1] ? 0x3F800000u : 0u);
            zi[s].y = (sp[2] ? 0x3F80u : 0u) | (sp[3] ? 0x3F800000u : 0u);
        }
#pragma unroll
        for (int s = 0; s < CH; ++s)
            *(uint2*)&zw[s * 2048 + zwofs] = zi[s];
    };

    // phase C(c): full-K g2 for step s = wv (two independent 2-MFMA chains).
    auto phaseC = [&](int c) {
        const int cb = c & 1;
        const u16* zr = &zb[cb][wv * 2048];
        const bf16x8 z0 = *(const bf16x8*)&zr[0 * 512 + zrofs];
        const bf16x8 z1 = *(const bf16x8*)&zr[1 * 512 + zrofs];
        const bf16x8 z2 = *(const bf16x8*)&zr[2 * 512 + zrofs];
        const bf16x8 z3 = *(const bf16x8*)&zr[3 * 512 + zrofs];
        __builtin_amdgcn_s_setprio(1);
        f32x4 ga = __builtin_amdgcn_mfma_f32_16x16x32_bf16(z0, w2f[0], zf, 0, 0, 0);
        f32x4 gb = __builtin_amdgcn_mfma_f32_16x16x32_bf16(z1, w2f[1], zf, 0, 0, 0);
        ga = __builtin_amdgcn_mfma_f32_16x16x32_bf16(z2, w2f[2], ga, 0, 0, 0);
        gb = __builtin_amdgcn_mfma_f32_16x16x32_bf16(z3, w2f[3], gb, 0, 0, 0);
        __builtin_amdgcn_s_setprio(0);
        const f32x4 g2 = ga + gb;
        u16* dst = g2p + (size_t)half * (T_STEPS * SLAB)
                 + (size_t)(c * CH + wv) * SLAB + (row0 + 4 * hi) * OUT_F + l15;
#pragma unroll
        for (int r = 0; r < 4; ++r) dst[r * OUT_F] = f2bf(g2[r]);
    };

    lds_barrier();     // prologue xl[0] staging visible
    phaseA(0);

    for (int c = 0; c < NCH; ++c) {
        lds_barrier();
        // Window (BAR(c), BAR(c+1)): writes {xl[c&1] (stage c+2), zb[(c+1)&1]};
        // reads {xl[(c+1)&1] (A-compute), zb[c&1] (C)} -- disjoint either order.
        if ((wv & 1) == 0) {
            if (c + 1 < NCH) phaseA(c + 1);
            phaseC(c);
        } else {
            phaseC(c);
            if (c + 1 < NCH) phaseA(c + 1);
        }
    }

    // spikes: wave-uniform u32 partial, one store per wave, no atomics
    if (lane == 0) spart[blockIdx.x * 8 + wv] = (u32)wcnt;
}

// Kernel 2: LI recurrence + max over t (one thread per (row,out) chain,
// summing the 2 half-slabs); block 0 additionally reduces the 2048 spike
// partials and writes spikes_mean.
__global__ void __launch_bounds__(256)
snn_li_kernel(const u16* __restrict__ g2p, const u32* __restrict__ spart,
              float* __restrict__ out)
{
    const int gid = blockIdx.x * 256 + threadIdx.x;    // 0..32767
    const u16* p0 = g2p + gid;
    const u16* p1 = p0 + (size_t)T_STEPS * SLAB;
    const float dt_tau = (float)(0.001 * (1.0 / 0.006));
    const float decay  = (float)(1.0 - 0.001 * (1.0 / 0.006));
    float v2 = 0.f, i2 = 0.f, ymax = -1e30f;
#pragma unroll 8
    for (int t = 0; t < T_STEPS; ++t) {
        const size_t o = (size_t)t * SLAB;
        const float g = bf2f(p0[o]) + bf2f(p1[o]);
        v2 = fmaf(dt_tau, i2 - v2, v2);   // uses old i2, matches reference
        ymax = fmaxf(ymax, v2);
        i2 = i2 * decay + g;
    }
    out[gid] = ymax;

    if (blockIdx.x == 0) {
        u32 s = 0;
#pragma unroll
        for (int i = 0; i < 8; ++i) s += spart[threadIdx.x * 8 + i];
#pragma unroll
        for (int m = 1; m < 64; m <<= 1) s += __shfl_xor(s, m, 64);
        __shared__ u32 sb[4];
        if ((threadIdx.x & 63) == 0) sb[threadIdx.x >> 6] = s;
        __syncthreads();
        if (threadIdx.x == 0)
            out[BATCH * OUT_F] =
                (float)(sb[0] + sb[1] + sb[2] + sb[3]) * (1.0f / BATCH);
    }
}

extern "C" void kernel_launch(void* const* d_in, const int* in_sizes, int n_in,
                              void* d_out, int out_size, void* d_ws, size_t ws_size,
                              hipStream_t stream) {
    const float* x  = (const float*)d_in[0];
    const float* w1 = (const float*)d_in[1];
    const float* w2 = (const float*)d_in[2];
    float* out = (float*)d_out;
    u16* g2p   = (u16*)d_ws;                         // 16.8 MB of slabs
    u32* spart = (u32*)((char*)d_ws + SPART_OFS);    // 2048 u32 partials

    hipLaunchKernelGGL(snn_l1_kernel, dim3(256), dim3(512), 0, stream,
                       x, w1, w2, g2p, spart);
    hipLaunchKernelGGL(snn_li_kernel, dim3(BATCH * OUT_F / 256), dim3(256), 0,
                       stream, g2p, spart, out);
}